// Round 3
// baseline (119.213 us; speedup 1.0000x reference)
//
#include <hip/hip_runtime.h>
#include <stdint.h>

#define N_ROWS 4096
#define D_DIM  1024
#define N_CAND 8192
#define TEMP_INV 20.0f

#define BM 256
#define BN 256
#define BK 64
#define NITER 8  // 16 K-tiles, 2 per iteration

typedef __attribute__((ext_vector_type(8))) _Float16 f16x8;
typedef __attribute__((ext_vector_type(4))) float    f32x4;
typedef __attribute__((ext_vector_type(4))) unsigned short us4;

using gvoid = __attribute__((address_space(1))) void;
using lvoid = __attribute__((address_space(3))) void;

__device__ __forceinline__ unsigned short f2h_bits(float f) {
  _Float16 h = (_Float16)f;
  return __builtin_bit_cast(unsigned short, h);
}

#define BAR() __builtin_amdgcn_s_barrier()
#define LGKM0() do { asm volatile("s_waitcnt lgkmcnt(0)" ::: "memory"); \
                     __builtin_amdgcn_sched_barrier(0); } while (0)

// ---------------------------------------------------------------------------
// Kernel 1: normalize rows, convert to fp16, pack cand=[P;N]; zero rowsum.
// ---------------------------------------------------------------------------
__global__ __launch_bounds__(256) void prep_kernel(
    const float* __restrict__ s, const float* __restrict__ p,
    const float* __restrict__ ng, unsigned short* __restrict__ s_h,
    unsigned short* __restrict__ cand_h, float* __restrict__ rowsum) {
  const int row = blockIdx.x;
  const int t = threadIdx.x;
  const float* src;
  unsigned short* dst;
  if (row < N_ROWS) {
    src = s + (size_t)row * D_DIM;
    dst = s_h + (size_t)row * D_DIM;
  } else if (row < 2 * N_ROWS) {
    src = p + (size_t)(row - N_ROWS) * D_DIM;
    dst = cand_h + (size_t)(row - N_ROWS) * D_DIM;
  } else {
    src = ng + (size_t)(row - 2 * N_ROWS) * D_DIM;
    dst = cand_h + (size_t)(row - N_ROWS) * D_DIM;
  }

  float4 v = reinterpret_cast<const float4*>(src)[t];
  float ss = v.x * v.x + v.y * v.y + v.z * v.z + v.w * v.w;
#pragma unroll
  for (int m = 32; m >= 1; m >>= 1) ss += __shfl_xor(ss, m, 64);
  __shared__ float red[4];
  const int w = t >> 6, l = t & 63;
  if (l == 0) red[w] = ss;
  __syncthreads();
  const float tot = red[0] + red[1] + red[2] + red[3];
  const float scale = 1.0f / fmaxf(sqrtf(tot), 1e-8f);

  us4 o;
  o[0] = f2h_bits(v.x * scale);
  o[1] = f2h_bits(v.y * scale);
  o[2] = f2h_bits(v.z * scale);
  o[3] = f2h_bits(v.w * scale);
  reinterpret_cast<us4*>(dst)[t] = o;

  if (t == 0 && row < N_ROWS) rowsum[row] = 0.0f;
}

// ---------------------------------------------------------------------------
// Kernel 2: fused GEMM + exp-rowsum. 256x256 tile, BK=64, 8 waves (2Mx4N),
// m201-style 8-phase schedule: per iter = 2 K-tiles; each phase =
// {quadrant ds_reads | 1-2 half-tile global_load_lds stages | barrier |
//  lgkmcnt(0) | setprio(1) 16xMFMA setprio(0) | barrier}; counted vmcnt(2)
// at phases 3 and 7 only (never 0 in steady state).
// LDS: buf0=[A(32K)|B(32K)] even tiles, buf1 odd tiles; XOR slot swizzle.
// ---------------------------------------------------------------------------
__global__ __launch_bounds__(512, 2) void gemm_lse_kernel(
    const unsigned short* __restrict__ s_h,
    const unsigned short* __restrict__ cand_h,
    float* __restrict__ rowsum, float* __restrict__ pos) {
  __shared__ __align__(16) unsigned char lds[2 * 2 * BM * BK * 2];  // 128 KiB

  const int t = threadIdx.x;
  const int w = t >> 6;
  const int l = t & 63;
  const int g = l >> 4;   // k-slice group
  const int rl = l & 15;  // lane within group
  const int wm = w >> 2;  // wave M half (0..1)
  const int wn = w & 3;   // wave N quarter (0..3)
  const int rowBase = blockIdx.y * BM;
  const int colBase = blockIdx.x * BN;

  f32x4 acc[8][4] = {};
  f16x8 af[4][2];       // A frags, current mh
  f16x8 bf0[2][2];      // B frags nh=0
  f16x8 bf1[2][2];      // B frags nh=1

  // --- stage one half-tile (128 rows x 64 cols) = 2 global_load_lds/thread
  auto stageA = [&](int kt, int h, int b) {
#pragma unroll
    for (int i = 0; i < 2; ++i) {
      const int s = i * 512 + t;             // slot in half (0..1023)
      const int rloc = s >> 3;               // local row 0..127
      const int scl = (s & 7) ^ (rloc & 7);  // inverse-swizzled source slot
      const unsigned short* gp =
          s_h + (size_t)(rowBase + h * 128 + rloc) * D_DIM + kt + scl * 8;
      unsigned char* dst =
          lds + b * 65536 + h * 16384 + (size_t)(i * 512 + w * 64) * 16;
      __builtin_amdgcn_global_load_lds((const gvoid*)gp, (lvoid*)dst, 16, 0, 0);
    }
  };
  auto stageB = [&](int kt, int h, int b) {
#pragma unroll
    for (int i = 0; i < 2; ++i) {
      const int s = i * 512 + t;
      const int rloc = s >> 3;
      const int scl = (s & 7) ^ (rloc & 7);
      const unsigned short* gp =
          cand_h + (size_t)(colBase + h * 128 + rloc) * D_DIM + kt + scl * 8;
      unsigned char* dst = lds + b * 65536 + 32768 + h * 16384 +
                           (size_t)(i * 512 + w * 64) * 16;
      __builtin_amdgcn_global_load_lds((const gvoid*)gp, (lvoid*)dst, 16, 0, 0);
    }
  };

  auto loadA = [&](int mh, int b) {
    unsigned char* A = lds + b * 65536;
#pragma unroll
    for (int m2 = 0; m2 < 4; ++m2) {
      const int r = wm * 128 + (mh * 4 + m2) * 16 + rl;
#pragma unroll
      for (int kk = 0; kk < 2; ++kk) {
        const int sl = (kk * 4 + g) ^ (r & 7);
        af[m2][kk] = *reinterpret_cast<const f16x8*>(A + r * 128 + sl * 16);
      }
    }
  };
  auto loadB = [&](int nh, int b, f16x8 (&bf)[2][2]) {
    unsigned char* B = lds + b * 65536 + 32768;
#pragma unroll
    for (int n2 = 0; n2 < 2; ++n2) {
      const int r = wn * 64 + (nh * 2 + n2) * 16 + rl;
#pragma unroll
      for (int kk = 0; kk < 2; ++kk) {
        const int sl = (kk * 4 + g) ^ (r & 7);
        bf[n2][kk] = *reinterpret_cast<const f16x8*>(B + r * 128 + sl * 16);
      }
    }
  };
  auto quad = [&](int mh, int nh, f16x8 (&bf)[2][2]) {
    __builtin_amdgcn_s_setprio(1);
#pragma unroll
    for (int m2 = 0; m2 < 4; ++m2)
#pragma unroll
      for (int n2 = 0; n2 < 2; ++n2)
#pragma unroll
        for (int kk = 0; kk < 2; ++kk)
          acc[mh * 4 + m2][nh * 2 + n2] =
              __builtin_amdgcn_mfma_f32_16x16x32_f16(
                  af[m2][kk], bf[n2][kk], acc[mh * 4 + m2][nh * 2 + n2],
                  0, 0, 0);
    __builtin_amdgcn_s_setprio(0);
  };

  // --- prologue: T0 fully, A0(T1); wait T0 (leaves A0(T1) in flight).
  stageA(0, 0, 0); stageA(0, 1, 0); stageB(0, 0, 0); stageB(0, 1, 0);
  stageA(BK, 0, 1);
  asm volatile("s_waitcnt vmcnt(2)" ::: "memory");
  __builtin_amdgcn_sched_barrier(0);
  BAR();

  for (int it = 0; it < NITER; ++it) {
    const bool s2 = (it < NITER - 1);   // tiles T+2 / T+3 exist
    const int kt1 = (2 * it + 1) * BK;  // T+1
    const int kt2 = (2 * it + 2) * BK;  // T+2
    const int kt3 = (2 * it + 3) * BK;  // T+3

    // P0: quad(0,0) buf0 | 12 ds_reads | stage A1(T+1)->buf1
    loadA(0, 0); loadB(0, 0, bf0);
    stageA(kt1, 1, 1);
    asm volatile("s_waitcnt lgkmcnt(8)" ::: "memory");
    BAR(); LGKM0();
    quad(0, 0, bf0);
    BAR();

    // P1: quad(0,1) buf0 | 4 ds_reads | stage B0,B1(T+1)->buf1
    loadB(1, 0, bf1);
    stageB(kt1, 0, 1); stageB(kt1, 1, 1);
    BAR(); LGKM0();
    quad(0, 1, bf1);
    BAR();

    // P2: quad(1,0) buf0 | 8 ds_reads | stage A0(T+2)->buf0
    loadA(1, 0);
    if (s2) stageA(kt2, 0, 0);
    BAR(); LGKM0();
    quad(1, 0, bf0);
    BAR();

    // P3: quad(1,1) buf0 | 0 reads | wait: T+1 landed (8 oldest)
    BAR();
    quad(1, 1, bf1);
    if (s2) asm volatile("s_waitcnt vmcnt(2)" ::: "memory");
    else    asm volatile("s_waitcnt vmcnt(0)" ::: "memory");
    __builtin_amdgcn_sched_barrier(0);
    BAR();

    // P4: quad(0,0) buf1 | 12 ds_reads | stage A1(T+2)->buf0
    loadA(0, 1); loadB(0, 1, bf0);
    if (s2) stageA(kt2, 1, 0);
    asm volatile("s_waitcnt lgkmcnt(8)" ::: "memory");
    BAR(); LGKM0();
    quad(0, 0, bf0);
    BAR();

    // P5: quad(0,1) buf1 | 4 ds_reads | stage B0,B1(T+2)->buf0
    loadB(1, 1, bf1);
    if (s2) { stageB(kt2, 0, 0); stageB(kt2, 1, 0); }
    BAR(); LGKM0();
    quad(0, 1, bf1);
    BAR();

    // P6: quad(1,0) buf1 | 8 ds_reads | stage A0(T+3)->buf1 (half0 free)
    loadA(1, 1);
    if (s2) stageA(kt3, 0, 1);
    BAR(); LGKM0();
    quad(1, 0, bf0);
    BAR();

    // P7: quad(1,1) buf1 | 0 reads | wait: T+2 landed (leaves A0(T+3))
    BAR();
    quad(1, 1, bf1);
    if (s2) {
      asm volatile("s_waitcnt vmcnt(2)" ::: "memory");
      __builtin_amdgcn_sched_barrier(0);
    }
    BAR();
  }

  // --- epilogue: sim = acc*20; cosine<=1 -> fixed-max logsumexp at 20.
  // C/D layout: col = l&15, row = (l>>4)*4 + reg.
#pragma unroll
  for (int m = 0; m < 8; ++m) {
#pragma unroll
    for (int j = 0; j < 4; ++j) {
      const int rowg = rowBase + wm * 128 + m * 16 + g * 4 + j;
      float sm = 0.0f;
#pragma unroll
      for (int n = 0; n < 4; ++n) {
        const int colg = colBase + wn * 64 + n * 16 + rl;
        const float simv = acc[m][n][j] * TEMP_INV;
        if (colg == rowg) pos[rowg] = simv;
        sm += __expf(simv - TEMP_INV);
      }
      sm += __shfl_xor(sm, 1, 64);
      sm += __shfl_xor(sm, 2, 64);
      sm += __shfl_xor(sm, 4, 64);
      sm += __shfl_xor(sm, 8, 64);
      if (rl == 0) atomicAdd(&rowsum[rowg], sm);
    }
  }
}

// ---------------------------------------------------------------------------
// Kernel 3: loss = mean(20 + log(rowsum) - pos)
// ---------------------------------------------------------------------------
__global__ __launch_bounds__(1024) void loss_kernel(
    const float* __restrict__ rowsum, const float* __restrict__ pos,
    float* __restrict__ out) {
  const int t = threadIdx.x;
  float acc = 0.0f;
  for (int i = t; i < N_ROWS; i += 1024)
    acc += TEMP_INV + logf(rowsum[i]) - pos[i];
#pragma unroll
  for (int m = 32; m >= 1; m >>= 1) acc += __shfl_xor(acc, m, 64);
  __shared__ float red[16];
  const int w = t >> 6, l = t & 63;
  if (l == 0) red[w] = acc;
  __syncthreads();
  if (t == 0) {
    float tot = 0.0f;
#pragma unroll
    for (int i = 0; i < 16; ++i) tot += red[i];
    out[0] = tot / (float)N_ROWS;
  }
}

// ---------------------------------------------------------------------------
extern "C" void kernel_launch(void* const* d_in, const int* in_sizes, int n_in,
                              void* d_out, int out_size, void* d_ws,
                              size_t ws_size, hipStream_t stream) {
  (void)in_sizes; (void)n_in; (void)out_size; (void)ws_size;
  const float* s = (const float*)d_in[0];
  const float* p = (const float*)d_in[1];
  const float* ng = (const float*)d_in[2];

  unsigned short* s_h = (unsigned short*)d_ws;                    // 8 MB
  unsigned short* cand_h = s_h + (size_t)N_ROWS * D_DIM;          // 16 MB
  float* rowsum = (float*)(cand_h + (size_t)N_CAND * D_DIM);      // 16 KB
  float* pos = rowsum + N_ROWS;                                   // 16 KB
  float* out = (float*)d_out;

  prep_kernel<<<dim3(3 * N_ROWS), dim3(256), 0, stream>>>(s, p, ng, s_h,
                                                          cand_h, rowsum);
  gemm_lse_kernel<<<dim3(N_CAND / BN, N_ROWS / BM), dim3(512), 0, stream>>>(
      s_h, cand_h, rowsum, pos);
  loss_kernel<<<dim3(1), dim3(1024), 0, stream>>>(rowsum, pos, out);
}

// Round 4
// 93.305 us; speedup vs baseline: 1.2777x; 1.2777x over previous
//
#include <hip/hip_runtime.h>
#include <stdint.h>

#define N_ROWS 4096
#define D_DIM  1024
#define N_CAND 8192
#define TEMP_INV 20.0f

#define BM 256
#define BN 256
#define BK 64
#define NITER 8  // 16 K-tiles, 2 per iteration (even->buf0, odd->buf1)

typedef __attribute__((ext_vector_type(8))) _Float16 f16x8;
typedef __attribute__((ext_vector_type(4))) float    f32x4;
typedef __attribute__((ext_vector_type(4))) unsigned short us4;

using gvoid = __attribute__((address_space(1))) void;
using lvoid = __attribute__((address_space(3))) void;

__device__ __forceinline__ unsigned short f2h_bits(float f) {
  _Float16 h = (_Float16)f;
  return __builtin_bit_cast(unsigned short, h);
}

#define BAR() __builtin_amdgcn_s_barrier()
#define LGKM0() do { asm volatile("s_waitcnt lgkmcnt(0)" ::: "memory"); \
                     __builtin_amdgcn_sched_barrier(0); } while (0)

// ---------------------------------------------------------------------------
// Kernel 1: normalize rows, convert to fp16, pack cand=[P;N]; zero rowsum.
// ---------------------------------------------------------------------------
__global__ __launch_bounds__(256) void prep_kernel(
    const float* __restrict__ s, const float* __restrict__ p,
    const float* __restrict__ ng, unsigned short* __restrict__ s_h,
    unsigned short* __restrict__ cand_h, float* __restrict__ rowsum) {
  const int row = blockIdx.x;
  const int t = threadIdx.x;
  const float* src;
  unsigned short* dst;
  if (row < N_ROWS) {
    src = s + (size_t)row * D_DIM;
    dst = s_h + (size_t)row * D_DIM;
  } else if (row < 2 * N_ROWS) {
    src = p + (size_t)(row - N_ROWS) * D_DIM;
    dst = cand_h + (size_t)(row - N_ROWS) * D_DIM;
  } else {
    src = ng + (size_t)(row - 2 * N_ROWS) * D_DIM;
    dst = cand_h + (size_t)(row - N_ROWS) * D_DIM;
  }

  float4 v = reinterpret_cast<const float4*>(src)[t];
  float ss = v.x * v.x + v.y * v.y + v.z * v.z + v.w * v.w;
#pragma unroll
  for (int m = 32; m >= 1; m >>= 1) ss += __shfl_xor(ss, m, 64);
  __shared__ float red[4];
  const int w = t >> 6, l = t & 63;
  if (l == 0) red[w] = ss;
  __syncthreads();
  const float tot = red[0] + red[1] + red[2] + red[3];
  const float scale = 1.0f / fmaxf(sqrtf(tot), 1e-8f);

  us4 o;
  o[0] = f2h_bits(v.x * scale);
  o[1] = f2h_bits(v.y * scale);
  o[2] = f2h_bits(v.z * scale);
  o[3] = f2h_bits(v.w * scale);
  reinterpret_cast<us4*>(dst)[t] = o;

  if (t == 0 && row < N_ROWS) rowsum[row] = 0.0f;
}

// ---------------------------------------------------------------------------
// Kernel 2: fused GEMM + exp-rowsum. 256x256, BK=64, 8 waves (2Mx4N).
// 8-phase m201 schedule; quad order (0,0)(0,1)(1,1)(1,0) with single bf
// (reload nh0 once per K-tile) to keep frag liveness at 48 VGPR.
// Staging: 1-2 half-tiles per phase; vmcnt(2) waits placed >=2.5 phases
// after the youngest guarded load; vmcnt never drains to 0 in steady state.
// ---------------------------------------------------------------------------
__global__ __launch_bounds__(512, 2) void gemm_lse_kernel(
    const unsigned short* __restrict__ s_h,
    const unsigned short* __restrict__ cand_h,
    float* __restrict__ rowsum, float* __restrict__ pos) {
  __shared__ __align__(16) unsigned char lds[131072];  // 2buf x (A32K|B32K)

  const int t = threadIdx.x;
  const int w = t >> 6;
  const int l = t & 63;
  const int g = l >> 4;
  const int rl = l & 15;
  const int wm = w >> 2;
  const int wn = w & 3;
  const int rowBase = blockIdx.y * BM;
  const int colBase = blockIdx.x * BN;

  f32x4 acc[8][4] = {};
  f16x8 af[4][2];  // current mh's A frags (32 VGPR, live <=2 phases)
  f16x8 bf[2][2];  // current nh's B frags (16 VGPR, live <=2 phases)

  // --- hoisted per-thread staging constants (2 loads per half-tile) ---
  const int rloc0 = t >> 3;            // 0..63
  const int rloc1 = 64 + (t >> 3);     // 64..127
  const int scl0 = (t & 7) ^ (rloc0 & 7);
  const int scl1 = (t & 7) ^ (rloc1 & 7);
  const size_t offA0 = (size_t)(rowBase + rloc0) * D_DIM + scl0 * 8;
  const size_t offA1 = (size_t)(rowBase + rloc1) * D_DIM + scl1 * 8;
  const size_t offB0 = (size_t)(colBase + rloc0) * D_DIM + scl0 * 8;
  const size_t offB1 = (size_t)(colBase + rloc1) * D_DIM + scl1 * 8;
  const int dBase = w * 64 * 16;       // wave-uniform LDS slot base

  auto stageA = [&](int kt, int h, int b) {
    const size_t ho = (size_t)h * (128 * D_DIM) + kt;
    unsigned char* d0 = lds + b * 65536 + h * 16384 + dBase;
    __builtin_amdgcn_global_load_lds((const gvoid*)(s_h + offA0 + ho),
                                     (lvoid*)d0, 16, 0, 0);
    __builtin_amdgcn_global_load_lds((const gvoid*)(s_h + offA1 + ho),
                                     (lvoid*)(d0 + 8192), 16, 0, 0);
  };
  auto stageB = [&](int kt, int h, int b) {
    const size_t ho = (size_t)h * (128 * D_DIM) + kt;
    unsigned char* d0 = lds + b * 65536 + 32768 + h * 16384 + dBase;
    __builtin_amdgcn_global_load_lds((const gvoid*)(cand_h + offB0 + ho),
                                     (lvoid*)d0, 16, 0, 0);
    __builtin_amdgcn_global_load_lds((const gvoid*)(cand_h + offB1 + ho),
                                     (lvoid*)(d0 + 8192), 16, 0, 0);
  };

  auto loadA = [&](int mh, int b) {
    unsigned char* A = lds + b * 65536;
#pragma unroll
    for (int m2 = 0; m2 < 4; ++m2) {
      const int r = wm * 128 + (mh * 4 + m2) * 16 + rl;
#pragma unroll
      for (int kk = 0; kk < 2; ++kk) {
        const int sl = (kk * 4 + g) ^ (r & 7);
        af[m2][kk] = *reinterpret_cast<const f16x8*>(A + r * 128 + sl * 16);
      }
    }
  };
  auto loadB = [&](int nh, int b) {
    unsigned char* B = lds + b * 65536 + 32768;
#pragma unroll
    for (int n2 = 0; n2 < 2; ++n2) {
      const int r = wn * 64 + (nh * 2 + n2) * 16 + rl;
#pragma unroll
      for (int kk = 0; kk < 2; ++kk) {
        const int sl = (kk * 4 + g) ^ (r & 7);
        bf[n2][kk] = *reinterpret_cast<const f16x8*>(B + r * 128 + sl * 16);
      }
    }
  };
  auto quad = [&](int mh, int nh) {
    __builtin_amdgcn_s_setprio(1);
#pragma unroll
    for (int m2 = 0; m2 < 4; ++m2)
#pragma unroll
      for (int n2 = 0; n2 < 2; ++n2)
#pragma unroll
        for (int kk = 0; kk < 2; ++kk)
          acc[mh * 4 + m2][nh * 2 + n2] =
              __builtin_amdgcn_mfma_f32_16x16x32_f16(
                  af[m2][kk], bf[n2][kk], acc[mh * 4 + m2][nh * 2 + n2],
                  0, 0, 0);
    __builtin_amdgcn_s_setprio(0);
  };

  // --- prologue: tile0 (4 half-tiles) + A0(tile1); wait tile0 only.
  stageA(0, 0, 0); stageA(0, 1, 0); stageB(0, 0, 0); stageB(0, 1, 0);
  stageA(BK, 0, 1);
  asm volatile("s_waitcnt vmcnt(2)" ::: "memory");
  __builtin_amdgcn_sched_barrier(0);
  BAR();

  for (int it = 0; it < NITER; ++it) {
    const bool sN = (it < NITER - 1);   // tiles 2it+2 / 2it+3 exist
    const int ktO = (2 * it + 1) * BK;  // odd tile (this iter, buf1)
    const int ktE = (2 * it + 2) * BK;  // next even tile (buf0)
    const int ktO2 = (2 * it + 3) * BK; // next odd tile (buf1)

    // P0: quad(0,0) buf0 | 12 ds | stage A1(odd)->buf1
    loadA(0, 0); loadB(0, 0);
    stageA(ktO, 1, 1);
    asm volatile("s_waitcnt lgkmcnt(8)" ::: "memory");
    BAR(); LGKM0();
    quad(0, 0);
    BAR();

    // P1: quad(0,1) buf0 | 4 ds | stage B0,B1(odd)->buf1
    loadB(1, 0);
    stageB(ktO, 0, 1); stageB(ktO, 1, 1);
    BAR(); LGKM0();
    quad(0, 1);
    BAR();

    // P2: quad(1,1) buf0 (bf keeps nh1) | 8 ds | no stage
    loadA(1, 0);
    BAR(); LGKM0();
    quad(1, 1);
    BAR();

    // P3: quad(1,0) buf0 | 4 ds (reload nh0) | stage A0(even)->buf0 |
    //     wait: odd tile fully landed (youngest guarded load issued P1).
    loadB(0, 0);
    if (sN) {
      stageA(ktE, 0, 0);
      asm volatile("s_waitcnt vmcnt(2)" ::: "memory");
    } else {
      asm volatile("s_waitcnt vmcnt(0)" ::: "memory");
    }
    __builtin_amdgcn_sched_barrier(0);
    BAR(); LGKM0();
    quad(1, 0);
    BAR();

    // P4: quad(0,0) buf1 | 12 ds | stage A1(even)->buf0
    loadA(0, 1); loadB(0, 1);
    if (sN) stageA(ktE, 1, 0);
    asm volatile("s_waitcnt lgkmcnt(8)" ::: "memory");
    BAR(); LGKM0();
    quad(0, 0);
    BAR();

    // P5: quad(0,1) buf1 | 4 ds | stage B0,B1(even)->buf0
    loadB(1, 1);
    if (sN) { stageB(ktE, 0, 0); stageB(ktE, 1, 0); }
    BAR(); LGKM0();
    quad(0, 1);
    BAR();

    // P6: quad(1,1) buf1 | 8 ds | no stage
    loadA(1, 1);
    BAR(); LGKM0();
    quad(1, 1);
    BAR();

    // P7: quad(1,0) buf1 | 4 ds (reload nh0) | stage A0(odd')->buf1 |
    //     wait: even tile fully landed (youngest guarded load issued P5).
    loadB(0, 1);
    if (sN) {
      stageA(ktO2, 0, 1);
      asm volatile("s_waitcnt vmcnt(2)" ::: "memory");
      __builtin_amdgcn_sched_barrier(0);
    }
    BAR(); LGKM0();
    quad(1, 0);
    BAR();
  }

  // --- epilogue: sim = acc*20; cosine<=1 -> fixed-max logsumexp at 20.
  // C/D layout: col = l&15, row = (l>>4)*4 + reg.
  __syncthreads();
  float* red = reinterpret_cast<float*>(lds);
  if (t < 256) red[t] = 0.0f;
  __syncthreads();

#pragma unroll
  for (int m = 0; m < 8; ++m) {
#pragma unroll
    for (int j = 0; j < 4; ++j) {
      const int rloc = wm * 128 + m * 16 + g * 4 + j;
      const int rowg = rowBase + rloc;
      float sm = 0.0f;
#pragma unroll
      for (int n = 0; n < 4; ++n) {
        const int colg = colBase + wn * 64 + n * 16 + rl;
        const float simv = acc[m][n][j] * TEMP_INV;
        if (colg == rowg) pos[rowg] = simv;
        sm += __expf(simv - TEMP_INV);
      }
      sm += __shfl_xor(sm, 1, 64);
      sm += __shfl_xor(sm, 2, 64);
      sm += __shfl_xor(sm, 4, 64);
      sm += __shfl_xor(sm, 8, 64);
      if (rl == 0) atomicAdd(&red[rloc], sm);
    }
  }
  __syncthreads();
  if (t < 256) atomicAdd(&rowsum[rowBase + t], red[t]);
}

// ---------------------------------------------------------------------------
// Kernel 3: loss = mean(20 + log(rowsum) - pos)
// ---------------------------------------------------------------------------
__global__ __launch_bounds__(1024) void loss_kernel(
    const float* __restrict__ rowsum, const float* __restrict__ pos,
    float* __restrict__ out) {
  const int t = threadIdx.x;
  float acc = 0.0f;
  for (int i = t; i < N_ROWS; i += 1024)
    acc += TEMP_INV + logf(rowsum[i]) - pos[i];
#pragma unroll
  for (int m = 32; m >= 1; m >>= 1) acc += __shfl_xor(acc, m, 64);
  __shared__ float red[16];
  const int w = t >> 6, l = t & 63;
  if (l == 0) red[w] = acc;
  __syncthreads();
  if (t == 0) {
    float tot = 0.0f;
#pragma unroll
    for (int i = 0; i < 16; ++i) tot += red[i];
    out[0] = tot / (float)N_ROWS;
  }
}

// ---------------------------------------------------------------------------
extern "C" void kernel_launch(void* const* d_in, const int* in_sizes, int n_in,
                              void* d_out, int out_size, void* d_ws,
                              size_t ws_size, hipStream_t stream) {
  (void)in_sizes; (void)n_in; (void)out_size; (void)ws_size;
  const float* s = (const float*)d_in[0];
  const float* p = (const float*)d_in[1];
  const float* ng = (const float*)d_in[2];

  unsigned short* s_h = (unsigned short*)d_ws;                    // 8 MB
  unsigned short* cand_h = s_h + (size_t)N_ROWS * D_DIM;          // 16 MB
  float* rowsum = (float*)(cand_h + (size_t)N_CAND * D_DIM);      // 16 KB
  float* pos = rowsum + N_ROWS;                                   // 16 KB
  float* out = (float*)d_out;

  prep_kernel<<<dim3(3 * N_ROWS), dim3(256), 0, stream>>>(s, p, ng, s_h,
                                                          cand_h, rowsum);
  gemm_lse_kernel<<<dim3(N_CAND / BN, N_ROWS / BM), dim3(512), 0, stream>>>(
      s_h, cand_h, rowsum, pos);
  loss_kernel<<<dim3(1), dim3(1024), 0, stream>>>(rowsum, pos, out);
}

// Round 5
// 78.687 us; speedup vs baseline: 1.5150x; 1.1858x over previous
//
#include <hip/hip_runtime.h>
#include <stdint.h>

#define N_ROWS 4096
#define D_DIM  1024
#define N_CAND 8192
#define TEMP_INV 20.0f

#define BM 256
#define BN 256
#define BK 64
#define NITER 8  // 16 K-tiles, 2 per iteration, 4 LDS buffers (mod 4)

typedef __attribute__((ext_vector_type(4))) float    f32x4;
typedef __attribute__((ext_vector_type(2))) long     l64x2;

using gvoid = __attribute__((address_space(1))) void;
using lvoid = __attribute__((address_space(3))) void;

#define BAR() __builtin_amdgcn_s_barrier()
#define LGKM0() do { asm volatile("s_waitcnt lgkmcnt(0)" ::: "memory"); \
                     __builtin_amdgcn_sched_barrier(0); } while (0)

// ---------------------------------------------------------------------------
// Kernel 1: normalize rows, convert to fp8 e4m3, K-interleaved column order:
// within each 64-col group, logical col u = kk*32 + g*8 + j is stored at byte
// pos = g*16 + kk*8 + j  (so one 16B slot = {kk0 8B, kk1 8B} for one g).
// cand = [P; N]. Also zeroes rowsum.
// ---------------------------------------------------------------------------
__global__ __launch_bounds__(256) void prep_kernel(
    const float* __restrict__ s, const float* __restrict__ p,
    const float* __restrict__ ng, unsigned char* __restrict__ s_q,
    unsigned char* __restrict__ cand_q, float* __restrict__ rowsum) {
  const int row = blockIdx.x;
  const int t = threadIdx.x;
  const float* src;
  unsigned char* dst;
  if (row < N_ROWS) {
    src = s + (size_t)row * D_DIM;
    dst = s_q + (size_t)row * D_DIM;
  } else if (row < 2 * N_ROWS) {
    src = p + (size_t)(row - N_ROWS) * D_DIM;
    dst = cand_q + (size_t)(row - N_ROWS) * D_DIM;
  } else {
    src = ng + (size_t)(row - 2 * N_ROWS) * D_DIM;
    dst = cand_q + (size_t)(row - N_ROWS) * D_DIM;
  }

  float4 v = reinterpret_cast<const float4*>(src)[t];
  float ss = v.x * v.x + v.y * v.y + v.z * v.z + v.w * v.w;
#pragma unroll
  for (int m = 32; m >= 1; m >>= 1) ss += __shfl_xor(ss, m, 64);
  __shared__ float red[4];
  const int w = t >> 6, l = t & 63;
  if (l == 0) red[w] = ss;
  __syncthreads();
  const float tot = red[0] + red[1] + red[2] + red[3];
  const float scale = 1.0f / fmaxf(sqrtf(tot), 1e-8f);

  int pk = __builtin_amdgcn_cvt_pk_fp8_f32(v.x * scale, v.y * scale, 0, false);
  pk = __builtin_amdgcn_cvt_pk_fp8_f32(v.z * scale, v.w * scale, pk, true);
  // cols 4t..4t+3 -> permuted byte position (all 4 within one j-octet):
  const int pos = ((t >> 4) << 6) | (((t >> 1) & 3) << 4) |
                  (((t >> 3) & 1) << 3) | ((t & 1) << 2);
  *reinterpret_cast<unsigned*>(dst + pos) = (unsigned)pk;

  if (t == 0 && row < N_ROWS) rowsum[row] = 0.0f;
}

// ---------------------------------------------------------------------------
// Kernel 2: fused fp8 GEMM + exp-rowsum. 256x256, BK=64, 8 waves (2Mx4N).
// 4 LDS buffers of 32 KB (A 16K | B 16K), tiles staged 2 ahead; 4 phases per
// K-tile {ds_reads | 1 half-tile stage | BAR | lgkm0 | 16 MFMA | BAR};
// vmcnt(4) waits only at P3/P7 (loads issued 4-7 phases earlier).
// mfma_f32_16x16x32_fp8_fp8; zero bank conflicts via K-interleaved layout.
// ---------------------------------------------------------------------------
__global__ __launch_bounds__(512, 2) void gemm_lse_kernel(
    const unsigned char* __restrict__ s_q,
    const unsigned char* __restrict__ cand_q,
    float* __restrict__ rowsum, float* __restrict__ pos) {
  __shared__ __align__(16) unsigned char lds[131072];  // 4 x (A 16K | B 16K)

  const int t = threadIdx.x;
  const int w = t >> 6;
  const int l = t & 63;
  const int g = l >> 4;
  const int rl = l & 15;
  const int wm = w >> 2;
  const int wn = w & 3;
  const int rowBase = blockIdx.y * BM;
  const int colBase = blockIdx.x * BN;

  f32x4 acc[8][4] = {};
  long af[4][2];   // current mh A frags (16 VGPR)
  long bf0[2][2];  // nh=0 B frags (8 VGPR)
  long bf1[2][2];  // nh=1 B frags (8 VGPR)

  // staging: one 16B slot per thread per half-tile (128 rows x 64 B)
  const int sRow = t >> 2;   // 0..127
  const int sSlot = t & 3;   // 0..3
  const size_t gA0 = (size_t)(rowBase + sRow) * D_DIM + sSlot * 16;
  const size_t gB0 = (size_t)(colBase + sRow) * D_DIM + sSlot * 16;

  auto stageA = [&](int T, int h) {
    const unsigned char* src = s_q + gA0 + (size_t)h * (128 * D_DIM) + T * 64;
    unsigned char* dst = lds + (T & 3) * 32768 + h * 8192 + t * 16;
    __builtin_amdgcn_global_load_lds((const gvoid*)src, (lvoid*)dst, 16, 0, 0);
  };
  auto stageB = [&](int T, int h) {
    const unsigned char* src =
        cand_q + gB0 + (size_t)h * (128 * D_DIM) + T * 64;
    unsigned char* dst = lds + (T & 3) * 32768 + 16384 + h * 8192 + t * 16;
    __builtin_amdgcn_global_load_lds((const gvoid*)src, (lvoid*)dst, 16, 0, 0);
  };

  auto loadA = [&](int mh, int T) {
    const unsigned char* A = lds + (T & 3) * 32768;
#pragma unroll
    for (int m2 = 0; m2 < 4; ++m2) {
      const int r = wm * 128 + mh * 64 + m2 * 16 + rl;
      l64x2 v = *reinterpret_cast<const l64x2*>(A + r * 64 + g * 16);
      af[m2][0] = v[0];
      af[m2][1] = v[1];
    }
  };
  auto loadB = [&](int nh, int T, long (&bf)[2][2]) {
    const unsigned char* B = lds + (T & 3) * 32768 + 16384;
#pragma unroll
    for (int n2 = 0; n2 < 2; ++n2) {
      const int r = wn * 64 + nh * 32 + n2 * 16 + rl;
      l64x2 v = *reinterpret_cast<const l64x2*>(B + r * 64 + g * 16);
      bf[n2][0] = v[0];
      bf[n2][1] = v[1];
    }
  };
  auto quad = [&](int mh, int nh, long (&bf)[2][2]) {
    __builtin_amdgcn_s_setprio(1);
#pragma unroll
    for (int m2 = 0; m2 < 4; ++m2)
#pragma unroll
      for (int n2 = 0; n2 < 2; ++n2)
#pragma unroll
        for (int kk = 0; kk < 2; ++kk)
          acc[mh * 4 + m2][nh * 2 + n2] =
              __builtin_amdgcn_mfma_f32_16x16x32_fp8_fp8(
                  af[m2][kk], bf[n2][kk], acc[mh * 4 + m2][nh * 2 + n2],
                  0, 0, 0);
    __builtin_amdgcn_s_setprio(0);
  };

  // --- prologue: stage tiles 0,1 fully; wait tile 0 (4 younger in flight).
  stageA(0, 0); stageA(0, 1); stageB(0, 0); stageB(0, 1);
  stageA(1, 0); stageA(1, 1); stageB(1, 0); stageB(1, 1);
  asm volatile("s_waitcnt vmcnt(4)" ::: "memory");
  __builtin_amdgcn_sched_barrier(0);
  BAR();

  for (int it = 0; it < NITER; ++it) {
    const int tE = 2 * it;       // even tile (computed P0-P3)
    const int tO = 2 * it + 1;   // odd tile  (computed P4-P7)
    const int T2 = tE + 2;       // staged P0-P3
    const int T3 = tE + 3;       // staged P4-P7
    const bool sN = (it < NITER - 1);

    // P0: 6 ds | stage A0(T2)
    loadA(0, tE); loadB(0, tE, bf0);
    if (sN) stageA(T2, 0);
    BAR(); LGKM0();
    quad(0, 0, bf0);
    BAR();

    // P1: 2 ds | stage A1(T2)
    loadB(1, tE, bf1);
    if (sN) stageA(T2, 1);
    BAR(); LGKM0();
    quad(0, 1, bf1);
    BAR();

    // P2: 4 ds | stage B0(T2)
    loadA(1, tE);
    if (sN) stageB(T2, 0);
    BAR(); LGKM0();
    quad(1, 1, bf1);
    BAR();

    // P3: 0 ds | stage B1(T2) | wait: odd tile landed (4 T2 loads younger)
    if (sN) {
      stageB(T2, 1);
      asm volatile("s_waitcnt vmcnt(4)" ::: "memory");
    } else {
      asm volatile("s_waitcnt vmcnt(0)" ::: "memory");
    }
    __builtin_amdgcn_sched_barrier(0);
    BAR();
    quad(1, 0, bf0);
    BAR();

    // P4: 6 ds | stage A0(T3)
    loadA(0, tO); loadB(0, tO, bf0);
    if (sN) stageA(T3, 0);
    BAR(); LGKM0();
    quad(0, 0, bf0);
    BAR();

    // P5: 2 ds | stage A1(T3)
    loadB(1, tO, bf1);
    if (sN) stageA(T3, 1);
    BAR(); LGKM0();
    quad(0, 1, bf1);
    BAR();

    // P6: 4 ds | stage B0(T3)
    loadA(1, tO);
    if (sN) stageB(T3, 0);
    BAR(); LGKM0();
    quad(1, 1, bf1);
    BAR();

    // P7: 0 ds | stage B1(T3) | wait: T2 landed (4 T3 loads younger)
    if (sN) {
      stageB(T3, 1);
      asm volatile("s_waitcnt vmcnt(4)" ::: "memory");
    } else {
      asm volatile("s_waitcnt vmcnt(0)" ::: "memory");
    }
    __builtin_amdgcn_sched_barrier(0);
    BAR();
    quad(1, 0, bf0);
    BAR();
  }

  // --- epilogue: sim = acc*20; cosine<=1 -> fixed-max logsumexp at 20.
  // C/D layout: col = l&15, row = (l>>4)*4 + reg.
  __syncthreads();
  float* red = reinterpret_cast<float*>(lds);
  if (t < 256) red[t] = 0.0f;
  __syncthreads();

#pragma unroll
  for (int m = 0; m < 8; ++m) {
#pragma unroll
    for (int j = 0; j < 4; ++j) {
      const int rloc = wm * 128 + m * 16 + g * 4 + j;
      const int rowg = rowBase + rloc;
      float sm = 0.0f;
#pragma unroll
      for (int n = 0; n < 4; ++n) {
        const int colg = colBase + wn * 64 + n * 16 + rl;
        const float simv = acc[m][n][j] * TEMP_INV;
        if (colg == rowg) pos[rowg] = simv;
        sm += __expf(simv - TEMP_INV);
      }
      sm += __shfl_xor(sm, 1, 64);
      sm += __shfl_xor(sm, 2, 64);
      sm += __shfl_xor(sm, 4, 64);
      sm += __shfl_xor(sm, 8, 64);
      if (rl == 0) atomicAdd(&red[rloc], sm);
    }
  }
  __syncthreads();
  if (t < 256) atomicAdd(&rowsum[rowBase + t], red[t]);
}

// ---------------------------------------------------------------------------
// Kernel 3: loss = mean(20 + log(rowsum) - pos)
// ---------------------------------------------------------------------------
__global__ __launch_bounds__(1024) void loss_kernel(
    const float* __restrict__ rowsum, const float* __restrict__ pos,
    float* __restrict__ out) {
  const int t = threadIdx.x;
  float acc = 0.0f;
  for (int i = t; i < N_ROWS; i += 1024)
    acc += TEMP_INV + logf(rowsum[i]) - pos[i];
#pragma unroll
  for (int m = 32; m >= 1; m >>= 1) acc += __shfl_xor(acc, m, 64);
  __shared__ float red[16];
  const int w = t >> 6, l = t & 63;
  if (l == 0) red[w] = acc;
  __syncthreads();
  if (t == 0) {
    float tot = 0.0f;
#pragma unroll
    for (int i = 0; i < 16; ++i) tot += red[i];
    out[0] = tot / (float)N_ROWS;
  }
}

// ---------------------------------------------------------------------------
extern "C" void kernel_launch(void* const* d_in, const int* in_sizes, int n_in,
                              void* d_out, int out_size, void* d_ws,
                              size_t ws_size, hipStream_t stream) {
  (void)in_sizes; (void)n_in; (void)out_size; (void)ws_size;
  const float* s = (const float*)d_in[0];
  const float* p = (const float*)d_in[1];
  const float* ng = (const float*)d_in[2];

  unsigned char* s_q = (unsigned char*)d_ws;                      // 4 MB
  unsigned char* cand_q = s_q + (size_t)N_ROWS * D_DIM;           // 8 MB
  float* rowsum = (float*)(cand_q + (size_t)N_CAND * D_DIM);      // 16 KB
  float* pos = rowsum + N_ROWS;                                   // 16 KB
  float* out = (float*)d_out;

  prep_kernel<<<dim3(3 * N_ROWS), dim3(256), 0, stream>>>(s, p, ng, s_q,
                                                          cand_q, rowsum);
  gemm_lse_kernel<<<dim3(N_CAND / BN, N_ROWS / BM), dim3(512), 0, stream>>>(
      s_q, cand_q, rowsum, pos);
  loss_kernel<<<dim3(1), dim3(1024), 0, stream>>>(rowsum, pos, out);
}

// Round 6
// 77.789 us; speedup vs baseline: 1.5325x; 1.0115x over previous
//
#include <hip/hip_runtime.h>
#include <stdint.h>

#define N_ROWS 4096
#define D_DIM  1024
#define N_CAND 8192
#define TEMP_INV 20.0f

#define BM 256
#define BN 256
#define BK 64
#define NT 16  // K-tiles

typedef __attribute__((ext_vector_type(4))) float    f32x4;
typedef __attribute__((ext_vector_type(2))) long     l64x2;

using gvoid = __attribute__((address_space(1))) void;
using lvoid = __attribute__((address_space(3))) void;

#define BAR() __builtin_amdgcn_s_barrier()
#define SCHED0() __builtin_amdgcn_sched_barrier(0)

// ---------------------------------------------------------------------------
// Kernel 1: normalize rows, convert to fp8 e4m3, K-interleaved column order:
// within each 64-col group, logical col u = kk*32 + g*8 + j stored at byte
// pos = g*16 + kk*8 + j  (one 16B slot = {kk0 8B, kk1 8B} for one g).
// cand = [P; N]. Also zeroes rowsum.
// ---------------------------------------------------------------------------
__global__ __launch_bounds__(256) void prep_kernel(
    const float* __restrict__ s, const float* __restrict__ p,
    const float* __restrict__ ng, unsigned char* __restrict__ s_q,
    unsigned char* __restrict__ cand_q, float* __restrict__ rowsum) {
  const int row = blockIdx.x;
  const int t = threadIdx.x;
  const float* src;
  unsigned char* dst;
  if (row < N_ROWS) {
    src = s + (size_t)row * D_DIM;
    dst = s_q + (size_t)row * D_DIM;
  } else if (row < 2 * N_ROWS) {
    src = p + (size_t)(row - N_ROWS) * D_DIM;
    dst = cand_q + (size_t)(row - N_ROWS) * D_DIM;
  } else {
    src = ng + (size_t)(row - 2 * N_ROWS) * D_DIM;
    dst = cand_q + (size_t)(row - N_ROWS) * D_DIM;
  }

  float4 v = reinterpret_cast<const float4*>(src)[t];
  float ss = v.x * v.x + v.y * v.y + v.z * v.z + v.w * v.w;
#pragma unroll
  for (int m = 32; m >= 1; m >>= 1) ss += __shfl_xor(ss, m, 64);
  __shared__ float red[4];
  const int w = t >> 6, l = t & 63;
  if (l == 0) red[w] = ss;
  __syncthreads();
  const float tot = red[0] + red[1] + red[2] + red[3];
  const float scale = 1.0f / fmaxf(sqrtf(tot), 1e-8f);

  int pk = __builtin_amdgcn_cvt_pk_fp8_f32(v.x * scale, v.y * scale, 0, false);
  pk = __builtin_amdgcn_cvt_pk_fp8_f32(v.z * scale, v.w * scale, pk, true);
  // cols 4t..4t+3 -> permuted byte position (all 4 within one j-octet):
  const int pos = ((t >> 4) << 6) | (((t >> 1) & 3) << 4) |
                  (((t >> 3) & 1) << 3) | ((t & 1) << 2);
  *reinterpret_cast<unsigned*>(dst + pos) = (unsigned)pk;

  if (t == 0 && row < N_ROWS) rowsum[row] = 0.0f;
}

// ---------------------------------------------------------------------------
// Kernel 2: fused fp8 GEMM + exp-rowsum. 256x256, BK=64, 8 waves (2Mx4N).
// 4 LDS buffers (tile mod 4), staged 2 tiles ahead. 2 phases per K-tile,
// ONE barrier per phase (32 MFMA each); single counted vmcnt(4) per K-tile
// placed before the barrier that precedes the first read of tile T+1.
// Slot-XOR LDS swizzle (phys slot = logical ^ (row&3)): 2 lanes/bank = free.
// ---------------------------------------------------------------------------
__global__ __launch_bounds__(512, 2) void gemm_lse_kernel(
    const unsigned char* __restrict__ s_q,
    const unsigned char* __restrict__ cand_q,
    float* __restrict__ rowsum, float* __restrict__ pos) {
  __shared__ __align__(16) unsigned char lds[131072];  // 4 x (A 16K | B 16K)

  const int t = threadIdx.x;
  const int w = t >> 6;
  const int l = t & 63;
  const int g = l >> 4;
  const int rl = l & 15;
  const int wm = w >> 2;
  const int wn = w & 3;
  const int slot = g ^ (rl & 3);  // swizzled 16B-slot, lane-constant
  const int rowBase = blockIdx.y * BM;
  const int colBase = blockIdx.x * BN;

  f32x4 acc[8][4] = {};
  long af[4][2];   // current mh A frags (16 VGPR)
  long bf0[2][2];  // nh=0 B frags (8 VGPR)
  long bf1[2][2];  // nh=1 B frags (8 VGPR)

  // staging: thread t handles phys slot (t&3) of local row (t>>2); the
  // global source is inverse-swizzled so LDS dst stays linear (t*16).
  const int sRow = t >> 2;                    // 0..127
  const int sSlotL = (t & 3) ^ (sRow & 3);    // logical slot to fetch
  const size_t gA0 = (size_t)(rowBase + sRow) * D_DIM + sSlotL * 16;
  const size_t gB0 = (size_t)(colBase + sRow) * D_DIM + sSlotL * 16;

  auto stageA = [&](int T, int h) {
    const unsigned char* src = s_q + gA0 + (size_t)h * (128 * D_DIM) + T * 64;
    unsigned char* dst = lds + (T & 3) * 32768 + h * 8192 + t * 16;
    __builtin_amdgcn_global_load_lds((const gvoid*)src, (lvoid*)dst, 16, 0, 0);
  };
  auto stageB = [&](int T, int h) {
    const unsigned char* src =
        cand_q + gB0 + (size_t)h * (128 * D_DIM) + T * 64;
    unsigned char* dst = lds + (T & 3) * 32768 + 16384 + h * 8192 + t * 16;
    __builtin_amdgcn_global_load_lds((const gvoid*)src, (lvoid*)dst, 16, 0, 0);
  };

  auto loadA = [&](int mh, int T) {
    const unsigned char* A = lds + (T & 3) * 32768;
#pragma unroll
    for (int m2 = 0; m2 < 4; ++m2) {
      const int r = wm * 128 + mh * 64 + m2 * 16 + rl;
      l64x2 v = *reinterpret_cast<const l64x2*>(A + r * 64 + slot * 16);
      af[m2][0] = v[0];
      af[m2][1] = v[1];
    }
  };
  auto loadB = [&](int nh, int T, long (&bf)[2][2]) {
    const unsigned char* B = lds + (T & 3) * 32768 + 16384;
#pragma unroll
    for (int n2 = 0; n2 < 2; ++n2) {
      const int r = wn * 64 + nh * 32 + n2 * 16 + rl;
      l64x2 v = *reinterpret_cast<const l64x2*>(B + r * 64 + slot * 16);
      bf[n2][0] = v[0];
      bf[n2][1] = v[1];
    }
  };
  auto quad = [&](int mh, int nh, long (&bf)[2][2]) {
    __builtin_amdgcn_s_setprio(1);
#pragma unroll
    for (int m2 = 0; m2 < 4; ++m2)
#pragma unroll
      for (int n2 = 0; n2 < 2; ++n2)
#pragma unroll
        for (int kk = 0; kk < 2; ++kk)
          acc[mh * 4 + m2][nh * 2 + n2] =
              __builtin_amdgcn_mfma_f32_16x16x32_fp8_fp8(
                  af[m2][kk], bf[n2][kk], acc[mh * 4 + m2][nh * 2 + n2],
                  0, 0, 0);
    __builtin_amdgcn_s_setprio(0);
  };

  // --- prologue: stage tiles 0,1; wait tile 0 (tile 1's 4 stay in flight).
  stageA(0, 0); stageA(0, 1); stageB(0, 0); stageB(0, 1);
  stageA(1, 0); stageA(1, 1); stageB(1, 0); stageB(1, 1);
  asm volatile("s_waitcnt vmcnt(4)" ::: "memory");
  SCHED0();
  BAR(); SCHED0();

  for (int T = 0; T < NT; ++T) {
    const bool sN = (T + 2 < NT);

    // P_A: 8 ds | stage A0,A1(T+2) | 32 MFMA | BAR
    loadA(0, T); loadB(0, T, bf0); loadB(1, T, bf1);
    if (sN) { stageA(T + 2, 0); stageA(T + 2, 1); }
    quad(0, 0, bf0); quad(0, 1, bf1);
    BAR(); SCHED0();

    // P_B: 4 ds | stage B0,B1(T+2) | 32 MFMA | vmcnt(T+1 landed) | BAR
    loadA(1, T);
    if (sN) { stageB(T + 2, 0); stageB(T + 2, 1); }
    quad(1, 1, bf1); quad(1, 0, bf0);
    if (T <= NT - 3) {
      asm volatile("s_waitcnt vmcnt(4)" ::: "memory");  // T+1's 4 drained
    } else if (T == NT - 2) {
      asm volatile("s_waitcnt vmcnt(0)" ::: "memory");  // tail drain
    }
    SCHED0();
    BAR(); SCHED0();
  }

  // --- epilogue: sim = acc*20; cosine<=1 -> fixed-max logsumexp at 20.
  // C/D layout: col = l&15, row = (l>>4)*4 + reg.
  __syncthreads();
  float* red = reinterpret_cast<float*>(lds);
  if (t < 256) red[t] = 0.0f;
  __syncthreads();

#pragma unroll
  for (int m = 0; m < 8; ++m) {
#pragma unroll
    for (int j = 0; j < 4; ++j) {
      const int rloc = wm * 128 + m * 16 + g * 4 + j;
      const int rowg = rowBase + rloc;
      float sm = 0.0f;
#pragma unroll
      for (int n = 0; n < 4; ++n) {
        const int colg = colBase + wn * 64 + n * 16 + rl;
        const float simv = acc[m][n][j] * TEMP_INV;
        if (colg == rowg) pos[rowg] = simv;
        sm += __expf(simv - TEMP_INV);
      }
      sm += __shfl_xor(sm, 1, 64);
      sm += __shfl_xor(sm, 2, 64);
      sm += __shfl_xor(sm, 4, 64);
      sm += __shfl_xor(sm, 8, 64);
      if (rl == 0) atomicAdd(&red[rloc], sm);
    }
  }
  __syncthreads();
  if (t < 256) atomicAdd(&rowsum[rowBase + t], red[t]);
}

// ---------------------------------------------------------------------------
// Kernel 3: loss = mean(20 + log(rowsum) - pos)
// ---------------------------------------------------------------------------
__global__ __launch_bounds__(1024) void loss_kernel(
    const float* __restrict__ rowsum, const float* __restrict__ pos,
    float* __restrict__ out) {
  const int t = threadIdx.x;
  float acc = 0.0f;
  for (int i = t; i < N_ROWS; i += 1024)
    acc += TEMP_INV + logf(rowsum[i]) - pos[i];
#pragma unroll
  for (int m = 32; m >= 1; m >>= 1) acc += __shfl_xor(acc, m, 64);
  __shared__ float red[16];
  const int w = t >> 6, l = t & 63;
  if (l == 0) red[w] = acc;
  __syncthreads();
  if (t == 0) {
    float tot = 0.0f;
#pragma unroll
    for (int i = 0; i < 16; ++i) tot += red[i];
    out[0] = tot / (float)N_ROWS;
  }
}

// ---------------------------------------------------------------------------
extern "C" void kernel_launch(void* const* d_in, const int* in_sizes, int n_in,
                              void* d_out, int out_size, void* d_ws,
                              size_t ws_size, hipStream_t stream) {
  (void)in_sizes; (void)n_in; (void)out_size; (void)ws_size;
  const float* s = (const float*)d_in[0];
  const float* p = (const float*)d_in[1];
  const float* ng = (const float*)d_in[2];

  unsigned char* s_q = (unsigned char*)d_ws;                      // 4 MB
  unsigned char* cand_q = s_q + (size_t)N_ROWS * D_DIM;           // 8 MB
  float* rowsum = (float*)(cand_q + (size_t)N_CAND * D_DIM);      // 16 KB
  float* pos = rowsum + N_ROWS;                                   // 16 KB
  float* out = (float*)d_out;

  prep_kernel<<<dim3(3 * N_ROWS), dim3(256), 0, stream>>>(s, p, ng, s_q,
                                                          cand_q, rowsum);
  gemm_lse_kernel<<<dim3(N_CAND / BN, N_ROWS / BM), dim3(512), 0, stream>>>(
      s_q, cand_q, rowsum, pos);
  loss_kernel<<<dim3(1), dim3(1024), 0, stream>>>(rowsum, pos, out);
}

// Round 7
// 76.298 us; speedup vs baseline: 1.5625x; 1.0196x over previous
//
#include <hip/hip_runtime.h>
#include <stdint.h>

#define N_ROWS 4096
#define D_DIM  1024
#define N_CAND 8192
#define TEMP_INV 20.0f

#define BM 256
#define BN 256
#define BK 64
#define NT 16  // K-tiles

typedef __attribute__((ext_vector_type(4))) float    f32x4;
typedef __attribute__((ext_vector_type(2))) long     l64x2;

using gvoid = __attribute__((address_space(1))) void;
using lvoid = __attribute__((address_space(3))) void;

#define BAR() __builtin_amdgcn_s_barrier()
#define SCHED0() __builtin_amdgcn_sched_barrier(0)

// ---------------------------------------------------------------------------
// Kernel 1: normalize rows, convert to fp8 e4m3, K-interleaved column order:
// within each 64-col group, logical col u = kk*32 + g*8 + j stored at byte
// pos = g*16 + kk*8 + j  (one 16B slot = {kk0 8B, kk1 8B} for one g).
// cand = [P; N]. Also zeroes rowsum.
// ---------------------------------------------------------------------------
__global__ __launch_bounds__(256) void prep_kernel(
    const float* __restrict__ s, const float* __restrict__ p,
    const float* __restrict__ ng, unsigned char* __restrict__ s_q,
    unsigned char* __restrict__ cand_q, float* __restrict__ rowsum) {
  const int row = blockIdx.x;
  const int t = threadIdx.x;
  const float* src;
  unsigned char* dst;
  if (row < N_ROWS) {
    src = s + (size_t)row * D_DIM;
    dst = s_q + (size_t)row * D_DIM;
  } else if (row < 2 * N_ROWS) {
    src = p + (size_t)(row - N_ROWS) * D_DIM;
    dst = cand_q + (size_t)(row - N_ROWS) * D_DIM;
  } else {
    src = ng + (size_t)(row - 2 * N_ROWS) * D_DIM;
    dst = cand_q + (size_t)(row - N_ROWS) * D_DIM;
  }

  float4 v = reinterpret_cast<const float4*>(src)[t];
  float ss = v.x * v.x + v.y * v.y + v.z * v.z + v.w * v.w;
#pragma unroll
  for (int m = 32; m >= 1; m >>= 1) ss += __shfl_xor(ss, m, 64);
  __shared__ float red[4];
  const int w = t >> 6, l = t & 63;
  if (l == 0) red[w] = ss;
  __syncthreads();
  const float tot = red[0] + red[1] + red[2] + red[3];
  const float scale = 1.0f / fmaxf(sqrtf(tot), 1e-8f);

  int pk = __builtin_amdgcn_cvt_pk_fp8_f32(v.x * scale, v.y * scale, 0, false);
  pk = __builtin_amdgcn_cvt_pk_fp8_f32(v.z * scale, v.w * scale, pk, true);
  // cols 4t..4t+3 -> permuted byte position (all 4 within one j-octet):
  const int pos = ((t >> 4) << 6) | (((t >> 1) & 3) << 4) |
                  (((t >> 3) & 1) << 3) | ((t & 1) << 2);
  *reinterpret_cast<unsigned*>(dst + pos) = (unsigned)pk;

  if (t == 0 && row < N_ROWS) rowsum[row] = 0.0f;
}

// ---------------------------------------------------------------------------
// Kernel 2: fused fp8 GEMM + exp-rowsum. 256x256, BK=64, 8 waves (2Mx4N).
// 4 LDS buffers (tile mod 4), staged 2 tiles ahead; 2 phases per K-tile,
// one barrier per phase; counted vmcnt(4) once per K-tile (never 0 until
// tail). LDS slot placement: phys slot p = (g + (row>>1)) & 3 -- for every
// 8-lane quantum the (rl&1, p) pairs enumerate all 8 4-bank spans ->
// conflict-free b128 reads with 64 B rows. Reader slot is lane-constant
// (row bases are multiples of 16); staging inverse-permutes the global src.
// ---------------------------------------------------------------------------
__global__ __launch_bounds__(512, 2) void gemm_lse_kernel(
    const unsigned char* __restrict__ s_q,
    const unsigned char* __restrict__ cand_q,
    float* __restrict__ rowsum, float* __restrict__ pos) {
  __shared__ __align__(16) unsigned char lds[131072];  // 4 x (A 16K | B 16K)

  const int t = threadIdx.x;
  const int w = t >> 6;
  const int l = t & 63;
  const int g = l >> 4;
  const int rl = l & 15;
  const int wm = w >> 2;
  const int wn = w & 3;
  const int slot = (g + (rl >> 1)) & 3;  // phys 16B-slot, lane-constant
  const int rowBase = blockIdx.y * BM;
  const int colBase = blockIdx.x * BN;

  f32x4 acc[8][4] = {};
  long af[4][2];   // current mh A frags (16 VGPR)
  long bf0[2][2];  // nh=0 B frags (8 VGPR)
  long bf1[2][2];  // nh=1 B frags (8 VGPR)

  // staging: thread t writes phys slot (t&3) of local row (t>>2) at linear
  // LDS dst t*16; fetch the logical slot that belongs there:
  // logical = (phys - (row>>1)) & 3 = ((t&3) - (t>>3)) & 3.
  const int sRow = t >> 2;                      // 0..127
  const int sSlotL = ((t & 3) - (t >> 3)) & 3;  // logical slot to fetch
  const size_t gA0 = (size_t)(rowBase + sRow) * D_DIM + sSlotL * 16;
  const size_t gB0 = (size_t)(colBase + sRow) * D_DIM + sSlotL * 16;

  auto stageA = [&](int T, int h) {
    const unsigned char* src = s_q + gA0 + (size_t)h * (128 * D_DIM) + T * 64;
    unsigned char* dst = lds + (T & 3) * 32768 + h * 8192 + t * 16;
    __builtin_amdgcn_global_load_lds((const gvoid*)src, (lvoid*)dst, 16, 0, 0);
  };
  auto stageB = [&](int T, int h) {
    const unsigned char* src =
        cand_q + gB0 + (size_t)h * (128 * D_DIM) + T * 64;
    unsigned char* dst = lds + (T & 3) * 32768 + 16384 + h * 8192 + t * 16;
    __builtin_amdgcn_global_load_lds((const gvoid*)src, (lvoid*)dst, 16, 0, 0);
  };

  auto loadA = [&](int mh, int T) {
    const unsigned char* A = lds + (T & 3) * 32768;
#pragma unroll
    for (int m2 = 0; m2 < 4; ++m2) {
      const int r = wm * 128 + mh * 64 + m2 * 16 + rl;
      l64x2 v = *reinterpret_cast<const l64x2*>(A + r * 64 + slot * 16);
      af[m2][0] = v[0];
      af[m2][1] = v[1];
    }
  };
  auto loadB = [&](int nh, int T, long (&bf)[2][2]) {
    const unsigned char* B = lds + (T & 3) * 32768 + 16384;
#pragma unroll
    for (int n2 = 0; n2 < 2; ++n2) {
      const int r = wn * 64 + nh * 32 + n2 * 16 + rl;
      l64x2 v = *reinterpret_cast<const l64x2*>(B + r * 64 + slot * 16);
      bf[n2][0] = v[0];
      bf[n2][1] = v[1];
    }
  };
  auto quad = [&](int mh, int nh, long (&bf)[2][2]) {
    __builtin_amdgcn_s_setprio(1);
#pragma unroll
    for (int m2 = 0; m2 < 4; ++m2)
#pragma unroll
      for (int n2 = 0; n2 < 2; ++n2)
#pragma unroll
        for (int kk = 0; kk < 2; ++kk)
          acc[mh * 4 + m2][nh * 2 + n2] =
              __builtin_amdgcn_mfma_f32_16x16x32_fp8_fp8(
                  af[m2][kk], bf[n2][kk], acc[mh * 4 + m2][nh * 2 + n2],
                  0, 0, 0);
    __builtin_amdgcn_s_setprio(0);
  };

  // --- prologue: stage tiles 0,1; wait tile 0 (tile 1's 4 stay in flight).
  stageA(0, 0); stageA(0, 1); stageB(0, 0); stageB(0, 1);
  stageA(1, 0); stageA(1, 1); stageB(1, 0); stageB(1, 1);
  asm volatile("s_waitcnt vmcnt(4)" ::: "memory");
  SCHED0();
  BAR(); SCHED0();

  for (int T = 0; T < NT; ++T) {
    const bool sN = (T + 2 < NT);

    // P_A: 8 ds | stage A0,A1(T+2) | 32 MFMA | BAR
    loadA(0, T); loadB(0, T, bf0); loadB(1, T, bf1);
    if (sN) { stageA(T + 2, 0); stageA(T + 2, 1); }
    quad(0, 0, bf0); quad(0, 1, bf1);
    BAR(); SCHED0();

    // P_B: 4 ds | stage B0,B1(T+2) | 32 MFMA | vmcnt(T+1 landed) | BAR
    loadA(1, T);
    if (sN) { stageB(T + 2, 0); stageB(T + 2, 1); }
    quad(1, 1, bf1); quad(1, 0, bf0);
    if (T <= NT - 3) {
      asm volatile("s_waitcnt vmcnt(4)" ::: "memory");  // T+1's 4 drained
    } else if (T == NT - 2) {
      asm volatile("s_waitcnt vmcnt(0)" ::: "memory");  // tail drain
    }
    SCHED0();
    BAR(); SCHED0();
  }

  // --- epilogue: sim = acc*20; cosine<=1 -> fixed-max logsumexp at 20.
  // C/D layout: col = l&15, row = (l>>4)*4 + reg.
  __syncthreads();
  float* red = reinterpret_cast<float*>(lds);
  if (t < 256) red[t] = 0.0f;
  __syncthreads();

#pragma unroll
  for (int m = 0; m < 8; ++m) {
#pragma unroll
    for (int j = 0; j < 4; ++j) {
      const int rloc = wm * 128 + m * 16 + g * 4 + j;
      const int rowg = rowBase + rloc;
      float sm = 0.0f;
#pragma unroll
      for (int n = 0; n < 4; ++n) {
        const int colg = colBase + wn * 64 + n * 16 + rl;
        const float simv = acc[m][n][j] * TEMP_INV;
        if (colg == rowg) pos[rowg] = simv;
        sm += __expf(simv - TEMP_INV);
      }
      sm += __shfl_xor(sm, 1, 64);
      sm += __shfl_xor(sm, 2, 64);
      sm += __shfl_xor(sm, 4, 64);
      sm += __shfl_xor(sm, 8, 64);
      if (rl == 0) atomicAdd(&red[rloc], sm);
    }
  }
  __syncthreads();
  if (t < 256) atomicAdd(&rowsum[rowBase + t], red[t]);
}

// ---------------------------------------------------------------------------
// Kernel 3: loss = mean(20 + log(rowsum) - pos)
// ---------------------------------------------------------------------------
__global__ __launch_bounds__(1024) void loss_kernel(
    const float* __restrict__ rowsum, const float* __restrict__ pos,
    float* __restrict__ out) {
  const int t = threadIdx.x;
  float acc = 0.0f;
  for (int i = t; i < N_ROWS; i += 1024)
    acc += TEMP_INV + logf(rowsum[i]) - pos[i];
#pragma unroll
  for (int m = 32; m >= 1; m >>= 1) acc += __shfl_xor(acc, m, 64);
  __shared__ float red[16];
  const int w = t >> 6, l = t & 63;
  if (l == 0) red[w] = acc;
  __syncthreads();
  if (t == 0) {
    float tot = 0.0f;
#pragma unroll
    for (int i = 0; i < 16; ++i) tot += red[i];
    out[0] = tot / (float)N_ROWS;
  }
}

// ---------------------------------------------------------------------------
extern "C" void kernel_launch(void* const* d_in, const int* in_sizes, int n_in,
                              void* d_out, int out_size, void* d_ws,
                              size_t ws_size, hipStream_t stream) {
  (void)in_sizes; (void)n_in; (void)out_size; (void)ws_size;
  const float* s = (const float*)d_in[0];
  const float* p = (const float*)d_in[1];
  const float* ng = (const float*)d_in[2];

  unsigned char* s_q = (unsigned char*)d_ws;                      // 4 MB
  unsigned char* cand_q = s_q + (size_t)N_ROWS * D_DIM;           // 8 MB
  float* rowsum = (float*)(cand_q + (size_t)N_CAND * D_DIM);      // 16 KB
  float* pos = rowsum + N_ROWS;                                   // 16 KB
  float* out = (float*)d_out;

  prep_kernel<<<dim3(3 * N_ROWS), dim3(256), 0, stream>>>(s, p, ng, s_q,
                                                          cand_q, rowsum);
  gemm_lse_kernel<<<dim3(N_CAND / BN, N_ROWS / BM), dim3(512), 0, stream>>>(
      s_q, cand_q, rowsum, pos);
  loss_kernel<<<dim3(1), dim3(1024), 0, stream>>>(rowsum, pos, out);
}